// Round 4
// baseline (93.589 us; speedup 1.0000x reference)
//
#include <hip/hip_runtime.h>
#include <math.h>

#define WAVE 64
#define E    16            // elements per lane (4 x float4)
#define SPAN (WAVE * E)    // 1024 elements covered per wave
#define W    128           // window length
#define OUTS (SPAN - W)    // 896 outputs per wave
#define GL   (W / E)       // 8 lanes per 128-element window block

typedef float vfloat4 __attribute__((ext_vector_type(4)));  // clang-native for nontemporal builtin

// van Herk / Gil-Werman sliding min, W = 128 = one 8-lane block:
//   out[i] = min( P[i], S[i-W+1] )
// P = prefix-min within the 128-aligned block containing i,
// S = suffix-min within the 128-aligned block containing i-W+1.
// Wave base is a multiple of 128, so 8-lane groups are 128-aligned blocks.
// Interior waves (all but first/last) take a branchless path: no bounds
// checks on loads or stores (wave-uniform s_cbranch, zero divergence).
__global__ __launch_bounds__(256) void swmin_kernel(const float* __restrict__ x,
                                                    float* __restrict__ out,
                                                    int n) {
    const int wave_id = blockIdx.x * (blockDim.x / WAVE) + (threadIdx.x / WAVE);
    const int lane    = threadIdx.x & (WAVE - 1);
    const int g       = lane & (GL - 1);                 // lane index within 128-block
    const int base    = wave_id * OUTS - W;              // wave's first element
    const int lbase   = base + lane * E;                 // lane's first element

    const bool interior = (base >= 0) && (base + SPAN <= n);   // wave-uniform

    // ---- load 16 elements ----
    float v[E];
    if (interior) {
#pragma unroll
        for (int k = 0; k < E / 4; ++k) {
            const vfloat4 f = *reinterpret_cast<const vfloat4*>(x + lbase + 4 * k);
            v[4 * k + 0] = f.x; v[4 * k + 1] = f.y;
            v[4 * k + 2] = f.z; v[4 * k + 3] = f.w;
        }
    } else {
#pragma unroll
        for (int j = 0; j < E; ++j) {
            const int pos = lbase + j;
            v[j] = (pos >= 0 && pos < n) ? x[pos] : INFINITY;
        }
    }

    // ---- in-lane prefix and suffix mins ----
    float p[E], s[E];
    p[0] = v[0];
#pragma unroll
    for (int j = 1; j < E; ++j) p[j] = fminf(p[j - 1], v[j]);
    s[E - 1] = v[E - 1];
#pragma unroll
    for (int j = E - 2; j >= 0; --j) s[j] = fminf(s[j + 1], v[j]);
    const float tot = p[E - 1];   // min of this lane's 16 elements

    // ---- segmented (8-lane groups) min-scans of lane totals ----
    float a = tot;   // prefix: min(tot[group_start .. lane])
    {
        float t = __shfl_up(a, 1); if (g >= 1) a = fminf(a, t);
        t       = __shfl_up(a, 2); if (g >= 2) a = fminf(a, t);
        t       = __shfl_up(a, 4); if (g >= 4) a = fminf(a, t);
    }
    const float tpre = __shfl_up(a, 1);
    const float Epre = (g >= 1) ? tpre : INFINITY;   // exclusive prefix

    float b = tot;   // suffix: min(tot[lane .. group_end])
    {
        float t = __shfl_down(b, 1); if (g + 1 <= GL - 1) b = fminf(b, t);
        t       = __shfl_down(b, 2); if (g + 2 <= GL - 1) b = fminf(b, t);
        t       = __shfl_down(b, 4); if (g + 4 <= GL - 1) b = fminf(b, t);
    }
    const float tsuf = __shfl_down(b, 1);
    const float Esuf = (g <= GL - 2) ? tsuf : INFINITY;  // exclusive suffix

    // ---- fetch S[i-127] from 8 lanes back ----
    // i = lbase + j; i-127 is (lane-8)'s element j+1 for j<15, (lane-7)'s elem 0 for j=15.
    float R[E];
#pragma unroll
    for (int j = 0; j < E - 1; ++j)
        R[j] = __shfl_up(fminf(Esuf, s[j + 1]), GL);
    R[E - 1] = __shfl_up(fminf(Esuf, s[0]), GL - 1);

    // ---- combine and store: out[j] = min( min(Epre, p[j]), R[j] ) ----
    if (lane >= GL) {   // first 8 lanes (128 elements) are halo
        if (interior) {
#pragma unroll
            for (int k = 0; k < E / 4; ++k) {
                vfloat4 o;
                o.x = fminf(fminf(Epre, p[4 * k + 0]), R[4 * k + 0]);
                o.y = fminf(fminf(Epre, p[4 * k + 1]), R[4 * k + 1]);
                o.z = fminf(fminf(Epre, p[4 * k + 2]), R[4 * k + 2]);
                o.w = fminf(fminf(Epre, p[4 * k + 3]), R[4 * k + 3]);
                // out is never re-read: nontemporal store keeps L2 for input
                __builtin_nontemporal_store(o, reinterpret_cast<vfloat4*>(out + lbase + 4 * k));
            }
        } else {
#pragma unroll
            for (int j = 0; j < E; ++j) {
                const int pos = lbase + j;
                if (pos < n)   // pos >= 0 guaranteed for lane >= 8 when base >= -W
                    out[pos] = fminf(fminf(Epre, p[j]), R[j]);
            }
        }
    }
}

extern "C" void kernel_launch(void* const* d_in, const int* in_sizes, int n_in,
                              void* d_out, int out_size, void* d_ws, size_t ws_size,
                              hipStream_t stream) {
    const float* x = (const float*)d_in[0];
    float* out     = (float*)d_out;
    const int n    = in_sizes[0];

    const int waves_per_block = 256 / WAVE;                        // 4
    const int total_waves     = (n + OUTS - 1) / OUTS;             // 9363 for N=8.4M
    const int blocks          = (total_waves + waves_per_block - 1) / waves_per_block;

    swmin_kernel<<<blocks, 256, 0, stream>>>(x, out, n);
}

// Round 5
// 86.982 us; speedup vs baseline: 1.0760x; 1.0760x over previous
//
#include <hip/hip_runtime.h>
#include <math.h>

#define WAVE 64
#define E    16            // elements per lane (4 x float4)
#define SPAN (WAVE * E)    // 1024 elements covered per wave
#define W    128           // window length
#define OUTS (SPAN - W)    // 896 outputs per wave
#define GL   (W / E)       // 8 lanes per 128-element window block

// van Herk / Gil-Werman sliding min, W = 128 = one 8-lane block:
//   out[i] = min( P[i], S[i-W+1] )
// P = prefix-min within the 128-aligned block containing i,
// S = suffix-min within the 128-aligned block containing i-W+1.
// Wave base is a multiple of 128, so 8-lane groups are 128-aligned blocks.
// Interior waves take a branchless path (wave-uniform s_cbranch).
// NOTE: nontemporal stores measured a ~5 us REGRESSION on gfx950 (R4:
// 93.6 vs 88.5 us) — plain stores complete into L2 and drain lazily; keep them.
__global__ __launch_bounds__(256) void swmin_kernel(const float* __restrict__ x,
                                                    float* __restrict__ out,
                                                    int n) {
    const int wave_id = blockIdx.x * (blockDim.x / WAVE) + (threadIdx.x / WAVE);
    const int lane    = threadIdx.x & (WAVE - 1);
    const int g       = lane & (GL - 1);                 // lane index within 128-block
    const int base    = wave_id * OUTS - W;              // wave's first element
    const int lbase   = base + lane * E;                 // lane's first element

    const bool interior = (base >= 0) && (base + SPAN <= n);   // wave-uniform

    // ---- load 16 elements ----
    float v[E];
    if (interior) {
#pragma unroll
        for (int k = 0; k < E / 4; ++k) {
            const float4 f = *reinterpret_cast<const float4*>(x + lbase + 4 * k);
            v[4 * k + 0] = f.x; v[4 * k + 1] = f.y;
            v[4 * k + 2] = f.z; v[4 * k + 3] = f.w;
        }
    } else {
#pragma unroll
        for (int j = 0; j < E; ++j) {
            const int pos = lbase + j;
            v[j] = (pos >= 0 && pos < n) ? x[pos] : INFINITY;
        }
    }

    // ---- in-lane prefix and suffix mins ----
    float p[E], s[E];
    p[0] = v[0];
#pragma unroll
    for (int j = 1; j < E; ++j) p[j] = fminf(p[j - 1], v[j]);
    s[E - 1] = v[E - 1];
#pragma unroll
    for (int j = E - 2; j >= 0; --j) s[j] = fminf(s[j + 1], v[j]);
    const float tot = p[E - 1];   // min of this lane's 16 elements

    // ---- segmented (8-lane groups) min-scans of lane totals ----
    float a = tot;   // prefix: min(tot[group_start .. lane])
    {
        float t = __shfl_up(a, 1); if (g >= 1) a = fminf(a, t);
        t       = __shfl_up(a, 2); if (g >= 2) a = fminf(a, t);
        t       = __shfl_up(a, 4); if (g >= 4) a = fminf(a, t);
    }
    const float tpre = __shfl_up(a, 1);
    const float Epre = (g >= 1) ? tpre : INFINITY;   // exclusive prefix

    float b = tot;   // suffix: min(tot[lane .. group_end])
    {
        float t = __shfl_down(b, 1); if (g + 1 <= GL - 1) b = fminf(b, t);
        t       = __shfl_down(b, 2); if (g + 2 <= GL - 1) b = fminf(b, t);
        t       = __shfl_down(b, 4); if (g + 4 <= GL - 1) b = fminf(b, t);
    }
    const float tsuf = __shfl_down(b, 1);
    const float Esuf = (g <= GL - 2) ? tsuf : INFINITY;  // exclusive suffix

    // ---- fetch S[i-127] from 8 lanes back ----
    // i = lbase + j; i-127 is (lane-8)'s element j+1 for j<15, (lane-7)'s elem 0 for j=15.
    float R[E];
#pragma unroll
    for (int j = 0; j < E - 1; ++j)
        R[j] = __shfl_up(fminf(Esuf, s[j + 1]), GL);
    R[E - 1] = __shfl_up(fminf(Esuf, s[0]), GL - 1);

    // ---- combine and store: out[j] = min( min(Epre, p[j]), R[j] ) ----
    if (lane >= GL) {   // first 8 lanes (128 elements) are halo
        if (interior) {
#pragma unroll
            for (int k = 0; k < E / 4; ++k) {
                float4 o;
                o.x = fminf(fminf(Epre, p[4 * k + 0]), R[4 * k + 0]);
                o.y = fminf(fminf(Epre, p[4 * k + 1]), R[4 * k + 1]);
                o.z = fminf(fminf(Epre, p[4 * k + 2]), R[4 * k + 2]);
                o.w = fminf(fminf(Epre, p[4 * k + 3]), R[4 * k + 3]);
                *reinterpret_cast<float4*>(out + lbase + 4 * k) = o;
            }
        } else {
#pragma unroll
            for (int j = 0; j < E; ++j) {
                const int pos = lbase + j;
                if (pos < n)   // pos >= 0 guaranteed for lane >= 8 when base >= -W
                    out[pos] = fminf(fminf(Epre, p[j]), R[j]);
            }
        }
    }
}

extern "C" void kernel_launch(void* const* d_in, const int* in_sizes, int n_in,
                              void* d_out, int out_size, void* d_ws, size_t ws_size,
                              hipStream_t stream) {
    const float* x = (const float*)d_in[0];
    float* out     = (float*)d_out;
    const int n    = in_sizes[0];

    const int waves_per_block = 256 / WAVE;                        // 4
    const int total_waves     = (n + OUTS - 1) / OUTS;             // 9363 for N=8.4M
    const int blocks          = (total_waves + waves_per_block - 1) / waves_per_block;

    swmin_kernel<<<blocks, 256, 0, stream>>>(x, out, n);
}